// Round 3
// baseline (19558.908 us; speedup 1.0000x reference)
//
#include <hip/hip_runtime.h>
#include <hip/hip_fp16.h>
#include <hip/hip_cooperative_groups.h>
#include <cstdint>
#include <cstddef>

namespace cg = cooperative_groups;

typedef _Float16 half_t;
typedef _Float16 half8  __attribute__((ext_vector_type(8)));
typedef float    float4v __attribute__((ext_vector_type(4)));

#define HDIM   1024
#define INDIM  171
#define INPAD  192     // 171 padded to multiple of 32 (K-chunks), zero tail
#define OUTDIM 171
#define OUTPAD 176     // 171 padded to multiple of 16 (j-tiles), zero rows
#define BATCH  128
#define TWARM  100
#define GGEN   100
#define NSTEP  (TWARM + GGEN)

// ---------------------------------------------------------------------------
// Persistent cooperative kernel, 192 blocks x 512 threads, ONE grid.sync/step.
//   block = (cell, 16-wide hidx tile). 8 waves = 4 gates x 2 K-halves.
//   Reference quirk (cell2 reads OLD h0, cell3 reads OLD h1) -> all three
//   cells independent within a step.
//   Decoder fusion: x_{t+1} @ Wih1^T == h2_t @ (Wih1·Wdec)^T + Wih1·bdec, so
//   gen-step cell0 reads h2_old through precomputed Wcomb — the decoder's
//   d_out store is consumed by nothing on-device and runs CONCURRENTLY in the
//   next step (11 blocks), frame 99 in an epilogue. No xcur, no 2nd sync.
//   c fp32 (transposed [H][B], coalesced); h fp16 double-buffered.
// ---------------------------------------------------------------------------

struct Params {
  const half_t* __restrict__ wih0; const half_t* __restrict__ whh0;
  const half_t* __restrict__ wih1; const half_t* __restrict__ whh1;
  const half_t* __restrict__ wih2; const half_t* __restrict__ whh2;
  const half_t* __restrict__ wcomb;  // [4096][HDIM] = Wih1 @ Wdec, fp16
  const float*  __restrict__ bias;   // [4][4096]: c0-warm, c1, c2, c0-gen
  const half_t* __restrict__ wdec;   // [OUTPAD][HDIM], rows >= 171 zero
  const float*  __restrict__ bdec;   // [OUTPAD], entries >= 171 zero
  const half_t* __restrict__ xseq;   // [T][B][INPAD] warmup, cols >= 171 zero
  half_t*       __restrict__ h;      // [2][3][B][HDIM] double-buffered hidden
  float*        __restrict__ cT;     // [3][HDIM][B] cell states (fp32)
  float*        __restrict__ out;    // d_out: [B][G][OUTDIM]
};

__device__ __forceinline__ void decoder_tile(const Params& p, int buf, int ob,
                                             int wv, int lr, int lk, int frame) {
  const int b = wv * 16 + lr;          // 8 waves x 16 = 128 batch rows
  const half_t* ar = p.wdec + (size_t)(ob + lr) * HDIM + lk * 8;
  const half_t* hr = p.h + (((size_t)buf * 3 + 2) * BATCH + b) * HDIM + lk * 8;
  float4v dacc = (float4v){0.f, 0.f, 0.f, 0.f};
#pragma unroll 4
  for (int ci = 0; ci < (HDIM >> 5); ++ci) {
    const int k0 = ci * 32;
    half8 af = *(const half8*)(ar + k0);
    half8 bf = *(const half8*)(hr + k0);
    dacc = __builtin_amdgcn_mfma_f32_16x16x32_f16(af, bf, dacc, 0, 0, 0);
  }
  const int orow = ob + lk * 4;        // D: col = lane&15 (=b), row = lk*4+r
#pragma unroll
  for (int r = 0; r < 4; ++r)
    if (orow + r < OUTDIM)
      p.out[((size_t)b * GGEN + frame) * OUTDIM + orow + r] = dacc[r] + p.bdec[orow + r];
}

__global__ __launch_bounds__(512, 1) void lstm_main(Params p) {
  cg::grid_group grid = cg::this_grid();
  const int bid  = blockIdx.x;
  const int tid  = threadIdx.x;
  const int cell = bid >> 6;          // 0..2
  const int m0   = (bid & 63) << 4;   // hidx tile base
  const int wv   = tid >> 6;          // 0..7
  const int g    = wv & 3;            // gate (i,f,g,o)
  const int kh   = wv >> 2;           // K-half
  const int lane = tid & 63;
  const int lr   = lane & 15;         // MFMA: A-row / B-col / D-col
  const int lk   = lane >> 4;         // MFMA: k-group

  __shared__ float Glds[2][4][16][128];   // 64 KiB: [kh][gate][hidx][b]

  const half_t* Wa_w; const half_t* Wb;
  if      (cell == 0) { Wa_w = p.wih0; Wb = p.whh0; }
  else if (cell == 1) { Wa_w = p.wih1; Wb = p.whh1; }
  else                { Wa_w = p.wih2; Wb = p.whh2; }

  const int jb = g * HDIM + m0;               // gate row base in W
  // cell0 has two seg0 configs: warm (wih0, K=INPAD) and gen (wcomb, K=HDIM)
  const int ldA_w = (cell == 0) ? INPAD : HDIM;
  const half_t* arow0_w = Wa_w    + (size_t)(jb + lr) * ldA_w + lk * 8;
  const half_t* arow0_g = p.wcomb + (size_t)(jb + lr) * HDIM  + lk * 8;  // cell0 only
  const half_t* arow1   = Wb      + (size_t)(jb + lr) * HDIM  + lk * 8;
  const bool is_dec = (bid >= 64 && bid < 75);   // cell-1 blocks double as decoder
  const int  ob     = (bid - 64) * 16;

  for (int t = 0; t < NSTEP; ++t) {
    const int cur = t & 1;
    const int nxt = cur ^ 1;
    const bool gen = (t >= TWARM);

    // ---- concurrent decoder store of the PREVIOUS step's frame ----
    if (gen && t > TWARM && is_dec)
      decoder_tile(p, cur, ob, wv, lr, lk, t - TWARM - 1);

    // B operands: quirk means everything reads the PREVIOUS step's state.
    const half_t* B0;
    const half_t* arow0;
    int ldA0;
    if (cell == 0) {
      if (!gen) { B0 = p.xseq + (size_t)t * BATCH * INPAD;      arow0 = arow0_w; ldA0 = INPAD; }
      else      { B0 = p.h + (size_t)(cur * 3 + 2) * BATCH * HDIM; arow0 = arow0_g; ldA0 = HDIM; }
    } else {
      B0 = p.h + (size_t)(cur * 3 + (cell - 1)) * BATCH * HDIM;  arow0 = arow0_w; ldA0 = HDIM;
    }
    const half_t* B1 = p.h + (size_t)(cur * 3 + cell) * BATCH * HDIM;

    float4v acc[8];
#pragma unroll
    for (int i = 0; i < 8; ++i) acc[i] = (float4v){0.f, 0.f, 0.f, 0.f};

    // chunk range of this K-half, split across the two segments
    const int nc0 = ldA0 >> 5;
    const int ncH = (nc0 + (HDIM >> 5)) >> 1;   // even for both configs
    const int a0 = kh * ncH, a1 = a0 + ncH;
    const int s0a = a0 < nc0 ? a0 : nc0;
    const int s0b = a1 < nc0 ? a1 : nc0;
    const int s1a = (a0 > nc0 ? a0 : nc0) - nc0;
    const int s1b = (a1 > nc0 ? a1 : nc0) - nc0;

    { // segment 0: x (warm) / h2_old via Wcomb (gen) / previous layer's old h
      const half_t* br[8];
#pragma unroll
      for (int bt = 0; bt < 8; ++bt) br[bt] = B0 + (size_t)(bt * 16 + lr) * ldA0 + lk * 8;
#pragma unroll 2
      for (int ci = s0a; ci < s0b; ++ci) {
        const int k0 = ci * 32;
        half8 af = *(const half8*)(arow0 + k0);
#pragma unroll
        for (int bt = 0; bt < 8; ++bt) {
          half8 bf = *(const half8*)(br[bt] + k0);
          acc[bt] = __builtin_amdgcn_mfma_f32_16x16x32_f16(af, bf, acc[bt], 0, 0, 0);
        }
      }
    }
    { // segment 1: own old h
      const half_t* br[8];
#pragma unroll
      for (int bt = 0; bt < 8; ++bt) br[bt] = B1 + (size_t)(bt * 16 + lr) * HDIM + lk * 8;
#pragma unroll 2
      for (int ci = s1a; ci < s1b; ++ci) {
        const int k0 = ci * 32;
        half8 af = *(const half8*)(arow1 + k0);
#pragma unroll
        for (int bt = 0; bt < 8; ++bt) {
          half8 bf = *(const half8*)(br[bt] + k0);
          acc[bt] = __builtin_amdgcn_mfma_f32_16x16x32_f16(af, bf, acc[bt], 0, 0, 0);
        }
      }
    }

    // D-frag mapping (m89-verified): col = lane&15 (=batch), row = lk*4+r (=hidx)
#pragma unroll
    for (int bt = 0; bt < 8; ++bt)
#pragma unroll
      for (int r = 0; r < 4; ++r)
        Glds[kh][g][lk * 4 + r][bt * 16 + lr] = acc[bt][r];

    __syncthreads();

    // elementwise LSTM update: 16 hidx x 128 b = 2048 items over 512 threads
    const float* biasc = p.bias + ((cell == 0) ? (gen ? 3 : 0) : cell) * 4096;
    float hv[4];
#pragma unroll
    for (int s = 0; s < 4; ++s) {
      const int idx = tid + s * 512;
      const int hl = idx >> 7, b = idx & 127;
      const float gi = Glds[0][0][hl][b] + Glds[1][0][hl][b] + biasc[0 * HDIM + m0 + hl];
      const float gf = Glds[0][1][hl][b] + Glds[1][1][hl][b] + biasc[1 * HDIM + m0 + hl];
      const float gg = Glds[0][2][hl][b] + Glds[1][2][hl][b] + biasc[2 * HDIM + m0 + hl];
      const float go = Glds[0][3][hl][b] + Glds[1][3][hl][b] + biasc[3 * HDIM + m0 + hl];
      const float si = 1.f / (1.f + __expf(-gi));
      const float sf = 1.f / (1.f + __expf(-gf));
      const float tg = tanhf(gg);
      const float so = 1.f / (1.f + __expf(-go));
      float* cp = p.cT + ((size_t)cell * HDIM + m0 + hl) * BATCH + b;
      const float cn = sf * (*cp) + si * tg;
      *cp = cn;
      hv[s] = so * tanhf(cn);
    }
    __syncthreads();            // everyone done reading Glds
    half_t* hbuf = (half_t*)&Glds[0][0][0][0];   // reuse as [16][128] half
#pragma unroll
    for (int s = 0; s < 4; ++s) {
      const int idx = tid + s * 512;
      hbuf[(idx >> 7) * 128 + (idx & 127)] = (half_t)hv[s];
    }
    __syncthreads();
    // transpose to b-major fp16 rows for next step's MFMA B operand
    if (tid < 256) {
      const int b = tid & 127, seg = tid >> 7;
      half_t vals[8];
#pragma unroll
      for (int q = 0; q < 8; ++q) vals[q] = hbuf[(seg * 8 + q) * 128 + b];
      half_t* hd = p.h + ((size_t)(nxt * 3 + cell) * BATCH + b) * HDIM + m0 + seg * 8;
      *(half8*)hd = *(const half8*)vals;
    }

    grid.sync();   // ONE sync per step — publishes h(t+1) (and orders c/Glds reuse)
  }

  // epilogue: final frame's decoder (h published by the loop's last sync)
  if (is_dec)
    decoder_tile(p, NSTEP & 1, ob, wv, lr, lk, GGEN - 1);
}

// --------------------------- init / conversion -----------------------------

__global__ void k_cvt_pad(half_t* __restrict__ dst, const float* __restrict__ src,
                          int dcols, int srows, int scols, int n) {
  for (int i = blockIdx.x * blockDim.x + threadIdx.x; i < n; i += gridDim.x * blockDim.x) {
    const int r = i / dcols, c = i - r * dcols;
    const float v = (r < srows && c < scols) ? src[(size_t)r * scols + c] : 0.f;
    dst[i] = (half_t)v;
  }
}

__global__ void k_bias_add(float* __restrict__ dst, const float* __restrict__ a,
                           const float* __restrict__ b, int n) {
  const int i = blockIdx.x * blockDim.x + threadIdx.x;
  if (i < n) dst[i] = a[i] + b[i];
}

__global__ void k_bias_pad(float* __restrict__ dst, const float* __restrict__ src,
                           int nsrc, int n) {
  const int i = blockIdx.x * blockDim.x + threadIdx.x;
  if (i < n) dst[i] = (i < nsrc) ? src[i] : 0.f;
}

// Wcomb = Wih1 @ Wdec : (4096,171)x(171,1024) -> fp16 [4096][1024]
__global__ void k_wcomb(half_t* __restrict__ dst, const float* __restrict__ wih,
                        const float* __restrict__ wdec) {
  const int j0 = blockIdx.x * 4;       // 1024 blocks x 4 j-rows
  const int k  = threadIdx.x;          // 1024 threads = k
  float acc0 = 0.f, acc1 = 0.f, acc2 = 0.f, acc3 = 0.f;
  for (int c = 0; c < OUTDIM; ++c) {
    const float d = wdec[(size_t)c * HDIM + k];   // coalesced, L2-resident
    acc0 += wih[(size_t)(j0 + 0) * INDIM + c] * d;
    acc1 += wih[(size_t)(j0 + 1) * INDIM + c] * d;
    acc2 += wih[(size_t)(j0 + 2) * INDIM + c] * d;
    acc3 += wih[(size_t)(j0 + 3) * INDIM + c] * d;
  }
  dst[(size_t)(j0 + 0) * HDIM + k] = (half_t)acc0;
  dst[(size_t)(j0 + 1) * HDIM + k] = (half_t)acc1;
  dst[(size_t)(j0 + 2) * HDIM + k] = (half_t)acc2;
  dst[(size_t)(j0 + 3) * HDIM + k] = (half_t)acc3;
}

// gen-phase cell0 bias: bih + bhh + Wih1 @ bdec
__global__ void k_bgen(float* __restrict__ dst, const float* __restrict__ wih,
                       const float* __restrict__ bdec, const float* __restrict__ bih,
                       const float* __restrict__ bhh) {
  const int j = blockIdx.x * 256 + threadIdx.x;   // 16 x 256 = 4096
  float a = 0.f;
  for (int c = 0; c < OUTDIM; ++c) a += wih[(size_t)j * INDIM + c] * bdec[c];
  dst[j] = a + bih[j] + bhh[j];
}

// initial_seq [B][T][171] fp32 -> [T][B][INPAD] fp16 (zero-padded cols)
__global__ void k_xseq(half_t* __restrict__ dst, const float* __restrict__ src, int n) {
  for (int i = blockIdx.x * blockDim.x + threadIdx.x; i < n; i += gridDim.x * blockDim.x) {
    const int t   = i / (BATCH * INPAD);
    const int rem = i - t * BATCH * INPAD;
    const int b   = rem / INPAD;
    const int c   = rem - b * INPAD;
    const float v = (c < INDIM) ? src[((size_t)b * TWARM + t) * INDIM + c] : 0.f;
    dst[i] = (half_t)v;
  }
}

// ---------------------------------------------------------------------------

extern "C" void kernel_launch(void* const* d_in, const int* in_sizes, int n_in,
                              void* d_out, int out_size, void* d_ws, size_t ws_size,
                              hipStream_t stream) {
  const float* x_in = (const float*)d_in[0];
  const float* Wih1 = (const float*)d_in[1];
  const float* Whh1 = (const float*)d_in[2];
  const float* bih1 = (const float*)d_in[3];
  const float* bhh1 = (const float*)d_in[4];
  const float* Wih2 = (const float*)d_in[5];
  const float* Whh2 = (const float*)d_in[6];
  const float* bih2 = (const float*)d_in[7];
  const float* bhh2 = (const float*)d_in[8];
  const float* Wih3 = (const float*)d_in[9];
  const float* Whh3 = (const float*)d_in[10];
  const float* bih3 = (const float*)d_in[11];
  const float* bhh3 = (const float*)d_in[12];
  const float* Wdec = (const float*)d_in[13];
  const float* bdec = (const float*)d_in[14];
  // d_in[15] = generate_frames_number (fixed 100, compiled in)

  char* ws = (char*)d_ws;
  size_t off = 0;
  auto take = [&](size_t bytes) -> char* {
    char* p = ws + off;
    off += (bytes + 255) & ~(size_t)255;
    return p;
  };

  // zero-init region first (d_ws is poisoned 0xAA before every launch)
  half_t* h_st  = (half_t*)take((size_t)2 * 3 * BATCH * HDIM * sizeof(half_t));
  float*  cT    = (float*) take((size_t)3 * HDIM * BATCH * sizeof(float));
  const size_t zero_bytes = off;

  half_t* wih0h = (half_t*)take((size_t)4096 * INPAD * sizeof(half_t));
  half_t* whh0h = (half_t*)take((size_t)4096 * HDIM * sizeof(half_t));
  half_t* wih1h = (half_t*)take((size_t)4096 * HDIM * sizeof(half_t));
  half_t* whh1h = (half_t*)take((size_t)4096 * HDIM * sizeof(half_t));
  half_t* wih2h = (half_t*)take((size_t)4096 * HDIM * sizeof(half_t));
  half_t* whh2h = (half_t*)take((size_t)4096 * HDIM * sizeof(half_t));
  half_t* wcomb = (half_t*)take((size_t)4096 * HDIM * sizeof(half_t));
  half_t* wdech = (half_t*)take((size_t)OUTPAD * HDIM * sizeof(half_t));
  half_t* xseqh = (half_t*)take((size_t)TWARM * BATCH * INPAD * sizeof(half_t));
  float*  biasw = (float*) take((size_t)4 * 4096 * sizeof(float));
  float*  bdecw = (float*) take((size_t)OUTPAD * sizeof(float));

  if (ws_size < off) return;  // workspace too small (~62 MB needed) — bail visibly

  hipMemsetAsync(d_ws, 0, zero_bytes, stream);

  k_cvt_pad<<<1024, 256, 0, stream>>>(wih0h, Wih1, INPAD, 4096, INDIM, 4096 * INPAD);
  k_cvt_pad<<<4096, 256, 0, stream>>>(whh0h, Whh1, HDIM, 4096, HDIM, 4096 * HDIM);
  k_cvt_pad<<<4096, 256, 0, stream>>>(wih1h, Wih2, HDIM, 4096, HDIM, 4096 * HDIM);
  k_cvt_pad<<<4096, 256, 0, stream>>>(whh1h, Whh2, HDIM, 4096, HDIM, 4096 * HDIM);
  k_cvt_pad<<<4096, 256, 0, stream>>>(wih2h, Wih3, HDIM, 4096, HDIM, 4096 * HDIM);
  k_cvt_pad<<<4096, 256, 0, stream>>>(whh2h, Whh3, HDIM, 4096, HDIM, 4096 * HDIM);
  k_cvt_pad<<<1024, 256, 0, stream>>>(wdech, Wdec, HDIM, OUTDIM, HDIM, OUTPAD * HDIM);
  k_wcomb<<<1024, 1024, 0, stream>>>(wcomb, Wih1, Wdec);
  k_bias_add<<<16, 256, 0, stream>>>(biasw + 0 * 4096, bih1, bhh1, 4096);
  k_bias_add<<<16, 256, 0, stream>>>(biasw + 1 * 4096, bih2, bhh2, 4096);
  k_bias_add<<<16, 256, 0, stream>>>(biasw + 2 * 4096, bih3, bhh3, 4096);
  k_bgen<<<16, 256, 0, stream>>>(biasw + 3 * 4096, Wih1, bdec, bih1, bhh1);
  k_bias_pad<<<1, 256, 0, stream>>>(bdecw, bdec, OUTDIM, OUTPAD);
  k_xseq<<<2048, 256, 0, stream>>>(xseqh, x_in, TWARM * BATCH * INPAD);

  Params p;
  p.wih0 = wih0h; p.whh0 = whh0h;
  p.wih1 = wih1h; p.whh1 = whh1h;
  p.wih2 = wih2h; p.whh2 = whh2h;
  p.wcomb = wcomb;
  p.bias = biasw; p.wdec = wdech; p.bdec = bdecw;
  p.xseq = xseqh;
  p.h = h_st; p.cT = cT; p.out = (float*)d_out;

  void* args[] = { (void*)&p };
  hipLaunchCooperativeKernel((const void*)lstm_main, dim3(192), dim3(512),
                             args, 0, stream);
}

// Round 6
// 13178.862 us; speedup vs baseline: 1.4841x; 1.4841x over previous
//
#include <hip/hip_runtime.h>
#include <hip/hip_fp16.h>
#include <hip/hip_cooperative_groups.h>
#include <cstdint>
#include <cstddef>

namespace cg = cooperative_groups;

typedef _Float16 half_t;
typedef _Float16 half8  __attribute__((ext_vector_type(8)));
typedef float    float4v __attribute__((ext_vector_type(4)));

#define HDIM   1024
#define INDIM  171
#define INPAD  192     // 171 padded to multiple of 32, zero tail
#define OUTDIM 171
#define OUTPAD 176
#define BATCH  128
#define TWARM  100
#define GGEN   100
#define NSTEP  (TWARM + GGEN)
#define NCELLB 192     // 3 cells x 64 hidx-tiles
#define NDECB  11      // dedicated decoder blocks (on otherwise-idle CUs)
#define NBLK   (NCELLB + NDECB)

// ---------------------------------------------------------------------------
// Persistent cooperative kernel, 203 blocks x 512 threads, 1 grid.sync/step.
// Weights live in VGPRs (128 regs/lane), immune to the per-sync L2
// invalidation that caused 27 MB/step far-fetch (R3 rocprof: FETCH 5.45 GB,
// MfmaUtil 2.4%). Waves = 2 gate-pairs x 4 K-quarters; each B fragment feeds
// 2 MFMAs. Cross-quarter reduction via 64 KB LDS (2-phase, XOR swizzle).
// Warm cell0: kq<2 streams the tiny x-part (wih0, L2-hot), kq>=2 uses the
// SAME resident whh0 registers as the gen path.
// Decoder fusion: gen cell0 reads h2_old via Wcomb = Wih1@Wdec; d_out frames
// computed by 11 dedicated blocks concurrently (+ epilogue).
// ---------------------------------------------------------------------------

struct Params {
  const half_t* __restrict__ wih0; const half_t* __restrict__ whh0;
  const half_t* __restrict__ wih1; const half_t* __restrict__ whh1;
  const half_t* __restrict__ wih2; const half_t* __restrict__ whh2;
  const half_t* __restrict__ wcomb;  // [4096][HDIM] = Wih1 @ Wdec
  const float*  __restrict__ bias;   // [4][4096]: c0-warm, c1, c2, c0-gen
  const half_t* __restrict__ wdec;   // [OUTPAD][HDIM]
  const float*  __restrict__ bdec;   // [OUTPAD]
  const half_t* __restrict__ xseq;   // [T][B][INPAD]
  half_t*       __restrict__ h;      // [2][3][B][HDIM] double-buffered
  float*        __restrict__ cT;     // [3][HDIM][B]
  float*        __restrict__ out;    // [B][G][OUTDIM]
};

#define MFMA16(a, b, c) __builtin_amdgcn_mfma_f32_16x16x32_f16(a, b, c, 0, 0, 0)

__device__ __forceinline__ void decoder_tile(const Params& p, int buf, int ob,
                                             int wv, int lr, int lk, int frame) {
  const int b = wv * 16 + lr;
  const half_t* ar = p.wdec + (size_t)(ob + lr) * HDIM + lk * 8;
  const half_t* hr = p.h + (((size_t)buf * 3 + 2) * BATCH + b) * HDIM + lk * 8;
  float4v dacc = (float4v){0.f, 0.f, 0.f, 0.f};
#pragma unroll 4
  for (int ci = 0; ci < (HDIM >> 5); ++ci) {
    const int k0 = ci * 32;
    half8 af = *(const half8*)(ar + k0);
    half8 bf = *(const half8*)(hr + k0);
    dacc = MFMA16(af, bf, dacc);
  }
  const int orow = ob + lk * 4;        // D: col = lane&15 (=b), row = lk*4+r
#pragma unroll
  for (int r = 0; r < 4; ++r)
    if (orow + r < OUTDIM)
      p.out[((size_t)b * GGEN + frame) * OUTDIM + orow + r] = dacc[r] + p.bdec[orow + r];
}

__global__ __launch_bounds__(512, 2) void lstm_main(Params p) {
  cg::grid_group grid = cg::this_grid();
  const int bid  = blockIdx.x;
  const int tid  = threadIdx.x;
  const int wv   = tid >> 6;
  const int lane = tid & 63;
  const int ggrp = wv & 1;            // gate-pair: 0 -> (i,f), 1 -> (g,o)
  const int kq   = wv >> 1;           // K-quarter 0..3
  const int lr   = lane & 15;         // MFMA: A-row / B-col / D-col
  const int lk   = lane >> 4;         // MFMA: k-group

  __shared__ float Rlds[4][2][16][128];   // 64 KiB: [gate][kq-pair][hidx][b^swz]

  // ---------------- dedicated decoder blocks ----------------
  if (bid >= NCELLB) {
    const int ob = (bid - NCELLB) * 16;
    for (int t = 0; t < NSTEP; ++t) {
      if (t > TWARM) decoder_tile(p, t & 1, ob, wv, lr, lk, t - TWARM - 1);
      grid.sync();
    }
    decoder_tile(p, NSTEP & 1, ob, wv, lr, lk, GGEN - 1);
    return;
  }

  // ---------------- cell blocks ----------------
  const int cell = bid >> 6;          // 0..2
  const int m0   = (bid & 63) << 4;   // hidx tile base
  const int jb0  = (2 * ggrp + 0) * HDIM + m0 + lr;   // A row, gate 2g+0
  const int jb1  = (2 * ggrp + 1) * HDIM + m0 + lr;   // A row, gate 2g+1

  // Resident weights (cells 1/2 all steps; cell0: gen-seg0 = wcomb, seg1 = whh0
  // which is valid in BOTH phases):
  const half_t* S0 = (cell == 0) ? p.wcomb : (cell == 1 ? p.wih1 : p.wih2);
  const half_t* S1 = (cell == 0) ? p.whh0  : (cell == 1 ? p.whh1 : p.whh2);

  half8 wA0[16], wA1[16];   // 128 VGPRs resident weights (this wave's quarter)
  {
    const half_t* M  = (kq < 2) ? S0 : S1;
    const int     cb = (kq & 1) * 16;          // local chunk base
#pragma unroll
    for (int ci = 0; ci < 16; ++ci) {
      const size_t ko = (size_t)(cb + ci) * 32 + lk * 8;
      wA0[ci] = *(const half8*)(M + (size_t)jb0 * HDIM + ko);
      wA1[ci] = *(const half8*)(M + (size_t)jb1 * HDIM + ko);
    }
  }

  // Warm-phase cell0 x-part A rows (wih0, ld=INPAD; 1.5 MB, L2-hot stream)
  const half_t* aw00 = p.wih0 + (size_t)jb0 * INPAD + lk * 8;
  const half_t* aw01 = p.wih0 + (size_t)jb1 * INPAD + lk * 8;

  const int csw = (lk & 1) << 4;      // LDS column swizzle (4-way -> free 2-way)

  for (int t = 0; t < NSTEP; ++t) {
    const int cur = t & 1;
    const int nxt = cur ^ 1;
    const bool gen = (t >= TWARM);

    float4v acc0[8], acc1[8];
#pragma unroll
    for (int i = 0; i < 8; ++i) {
      acc0[i] = (float4v){0.f, 0.f, 0.f, 0.f};
      acc1[i] = (float4v){0.f, 0.f, 0.f, 0.f};
    }

    if (cell == 0 && !gen && kq < 2) {
      // ---- streamed x-part: chunks [kq*3, kq*3+3) of INPAD=192 ----
      const half_t* B0 = p.xseq + (size_t)t * BATCH * INPAD;
      const half_t* bx[8];
#pragma unroll
      for (int bt = 0; bt < 8; ++bt) bx[bt] = B0 + (size_t)(bt * 16 + lr) * INPAD + lk * 8;
#pragma unroll
      for (int ci = 0; ci < 3; ++ci) {
        const int ko = (kq * 3 + ci) * 32;
        half8 af0 = *(const half8*)(aw00 + ko);
        half8 af1 = *(const half8*)(aw01 + ko);
#pragma unroll
        for (int bt = 0; bt < 8; ++bt) {
          half8 bf = *(const half8*)(bx[bt] + ko);
          acc0[bt] = MFMA16(af0, bf, acc0[bt]);
          acc1[bt] = MFMA16(af1, bf, acc1[bt]);
        }
      }
    } else {
      // ---- resident-A path ----
      const half_t* bb;
      if (kq < 2) {
        bb = (cell == 0)
            ? p.h + (size_t)(cur * 3 + 2) * BATCH * HDIM            // h2_old (wcomb)
            : p.h + (size_t)(cur * 3 + (cell - 1)) * BATCH * HDIM;  // prev layer OLD h
      } else {
        bb = p.h + (size_t)(cur * 3 + cell) * BATCH * HDIM;         // own OLD h
      }
      const half_t* rb[8];
#pragma unroll
      for (int bt = 0; bt < 8; ++bt)
        rb[bt] = bb + (size_t)(bt * 16 + lr) * HDIM + (kq & 1) * 512 + lk * 8;
#pragma unroll
      for (int ci = 0; ci < 16; ++ci) {
#pragma unroll
        for (int bt = 0; bt < 8; ++bt) {
          half8 bf = *(const half8*)(rb[bt] + ci * 32);
          acc0[bt] = MFMA16(wA0[ci], bf, acc0[bt]);
          acc1[bt] = MFMA16(wA1[ci], bf, acc1[bt]);
        }
      }
    }

    // ---- cross-quarter reduction in LDS (2 phases), D: col=lane&15, row=lk*4+r
    if (kq < 2) {
#pragma unroll
      for (int bt = 0; bt < 8; ++bt) {
        const int col = (bt * 16 + lr) ^ csw;
#pragma unroll
        for (int r = 0; r < 4; ++r) {
          Rlds[2 * ggrp + 0][kq][lk * 4 + r][col] = acc0[bt][r];
          Rlds[2 * ggrp + 1][kq][lk * 4 + r][col] = acc1[bt][r];
        }
      }
    }
    __syncthreads();
    if (kq >= 2) {
#pragma unroll
      for (int bt = 0; bt < 8; ++bt) {
        const int col = (bt * 16 + lr) ^ csw;
#pragma unroll
        for (int r = 0; r < 4; ++r) {
          Rlds[2 * ggrp + 0][kq - 2][lk * 4 + r][col] += acc0[bt][r];
          Rlds[2 * ggrp + 1][kq - 2][lk * 4 + r][col] += acc1[bt][r];
        }
      }
    }
    __syncthreads();

    // ---- elementwise LSTM update: 2048 (hidx,b) cells over 512 threads ----
    const float* biasc = p.bias + ((cell == 0) ? (gen ? 3 : 0) : cell) * 4096;
    float hv[4];
#pragma unroll
    for (int s = 0; s < 4; ++s) {
      const int idx = tid + s * 512;
      const int hl = idx >> 7, b = idx & 127;
      const int bc = b ^ (((hl >> 2) & 1) << 4);
      const float gi = Rlds[0][0][hl][bc] + Rlds[0][1][hl][bc] + biasc[0 * HDIM + m0 + hl];
      const float gf = Rlds[1][0][hl][bc] + Rlds[1][1][hl][bc] + biasc[1 * HDIM + m0 + hl];
      const float gv = Rlds[2][0][hl][bc] + Rlds[2][1][hl][bc] + biasc[2 * HDIM + m0 + hl];
      const float go = Rlds[3][0][hl][bc] + Rlds[3][1][hl][bc] + biasc[3 * HDIM + m0 + hl];
      const float si = 1.f / (1.f + __expf(-gi));
      const float sf = 1.f / (1.f + __expf(-gf));
      const float tg = tanhf(gv);
      const float so = 1.f / (1.f + __expf(-go));
      float* cp = p.cT + ((size_t)cell * HDIM + m0 + hl) * BATCH + b;
      const float cn = sf * (*cp) + si * tg;
      *cp = cn;
      hv[s] = so * tanhf(cn);
    }
    __syncthreads();            // everyone done reading Rlds
    half_t* hbuf = (half_t*)&Rlds[0][0][0][0];   // reuse as [16][128] half
#pragma unroll
    for (int s = 0; s < 4; ++s) {
      const int idx = tid + s * 512;
      hbuf[(idx >> 7) * 128 + (idx & 127)] = (half_t)hv[s];
    }
    __syncthreads();
    // transpose to b-major fp16 rows for next step's MFMA B operand
    if (tid < 256) {
      const int b = tid & 127, seg = tid >> 7;
      half_t vals[8];
#pragma unroll
      for (int q = 0; q < 8; ++q) vals[q] = hbuf[(seg * 8 + q) * 128 + b];
      half_t* hd = p.h + ((size_t)(nxt * 3 + cell) * BATCH + b) * HDIM + m0 + seg * 8;
      *(half8*)hd = *(const half8*)vals;
    }

    grid.sync();   // ONE sync per step — publishes h(t+1)
  }
}

// --------------------------- init / conversion -----------------------------

__global__ void k_cvt_pad(half_t* __restrict__ dst, const float* __restrict__ src,
                          int dcols, int srows, int scols, int n) {
  for (int i = blockIdx.x * blockDim.x + threadIdx.x; i < n; i += gridDim.x * blockDim.x) {
    const int r = i / dcols, c = i - r * dcols;
    const float v = (r < srows && c < scols) ? src[(size_t)r * scols + c] : 0.f;
    dst[i] = (half_t)v;
  }
}

__global__ void k_bias_add(float* __restrict__ dst, const float* __restrict__ a,
                           const float* __restrict__ b, int n) {
  const int i = blockIdx.x * blockDim.x + threadIdx.x;
  if (i < n) dst[i] = a[i] + b[i];
}

__global__ void k_bias_pad(float* __restrict__ dst, const float* __restrict__ src,
                           int nsrc, int n) {
  const int i = blockIdx.x * blockDim.x + threadIdx.x;
  if (i < n) dst[i] = (i < nsrc) ? src[i] : 0.f;
}

// Wcomb = Wih1 @ Wdec : (4096,171)x(171,1024) -> fp16 [4096][1024]
__global__ void k_wcomb(half_t* __restrict__ dst, const float* __restrict__ wih,
                        const float* __restrict__ wdec) {
  const int j0 = blockIdx.x * 4;
  const int k  = threadIdx.x;
  float acc0 = 0.f, acc1 = 0.f, acc2 = 0.f, acc3 = 0.f;
  for (int c = 0; c < OUTDIM; ++c) {
    const float d = wdec[(size_t)c * HDIM + k];
    acc0 += wih[(size_t)(j0 + 0) * INDIM + c] * d;
    acc1 += wih[(size_t)(j0 + 1) * INDIM + c] * d;
    acc2 += wih[(size_t)(j0 + 2) * INDIM + c] * d;
    acc3 += wih[(size_t)(j0 + 3) * INDIM + c] * d;
  }
  dst[(size_t)(j0 + 0) * HDIM + k] = (half_t)acc0;
  dst[(size_t)(j0 + 1) * HDIM + k] = (half_t)acc1;
  dst[(size_t)(j0 + 2) * HDIM + k] = (half_t)acc2;
  dst[(size_t)(j0 + 3) * HDIM + k] = (half_t)acc3;
}

// gen-phase cell0 bias: bih + bhh + Wih1 @ bdec
__global__ void k_bgen(float* __restrict__ dst, const float* __restrict__ wih,
                       const float* __restrict__ bdec, const float* __restrict__ bih,
                       const float* __restrict__ bhh) {
  const int j = blockIdx.x * 256 + threadIdx.x;
  float a = 0.f;
  for (int c = 0; c < OUTDIM; ++c) a += wih[(size_t)j * INDIM + c] * bdec[c];
  dst[j] = a + bih[j] + bhh[j];
}

// initial_seq [B][T][171] fp32 -> [T][B][INPAD] fp16 (zero-padded cols)
__global__ void k_xseq(half_t* __restrict__ dst, const float* __restrict__ src, int n) {
  for (int i = blockIdx.x * blockDim.x + threadIdx.x; i < n; i += gridDim.x * blockDim.x) {
    const int t   = i / (BATCH * INPAD);
    const int rem = i - t * BATCH * INPAD;
    const int b   = rem / INPAD;
    const int c   = rem - b * INPAD;
    const float v = (c < INDIM) ? src[((size_t)b * TWARM + t) * INDIM + c] : 0.f;
    dst[i] = (half_t)v;
  }
}

// ---------------------------------------------------------------------------

extern "C" void kernel_launch(void* const* d_in, const int* in_sizes, int n_in,
                              void* d_out, int out_size, void* d_ws, size_t ws_size,
                              hipStream_t stream) {
  const float* x_in = (const float*)d_in[0];
  const float* Wih1 = (const float*)d_in[1];
  const float* Whh1 = (const float*)d_in[2];
  const float* bih1 = (const float*)d_in[3];
  const float* bhh1 = (const float*)d_in[4];
  const float* Wih2 = (const float*)d_in[5];
  const float* Whh2 = (const float*)d_in[6];
  const float* bih2 = (const float*)d_in[7];
  const float* bhh2 = (const float*)d_in[8];
  const float* Wih3 = (const float*)d_in[9];
  const float* Whh3 = (const float*)d_in[10];
  const float* bih3 = (const float*)d_in[11];
  const float* bhh3 = (const float*)d_in[12];
  const float* Wdec = (const float*)d_in[13];
  const float* bdec = (const float*)d_in[14];

  char* ws = (char*)d_ws;
  size_t off = 0;
  auto take = [&](size_t bytes) -> char* {
    char* p = ws + off;
    off += (bytes + 255) & ~(size_t)255;
    return p;
  };

  // zero-init region first (d_ws is poisoned 0xAA before every launch)
  half_t* h_st  = (half_t*)take((size_t)2 * 3 * BATCH * HDIM * sizeof(half_t));
  float*  cT    = (float*) take((size_t)3 * HDIM * BATCH * sizeof(float));
  const size_t zero_bytes = off;

  half_t* wih0h = (half_t*)take((size_t)4096 * INPAD * sizeof(half_t));
  half_t* whh0h = (half_t*)take((size_t)4096 * HDIM * sizeof(half_t));
  half_t* wih1h = (half_t*)take((size_t)4096 * HDIM * sizeof(half_t));
  half_t* whh1h = (half_t*)take((size_t)4096 * HDIM * sizeof(half_t));
  half_t* wih2h = (half_t*)take((size_t)4096 * HDIM * sizeof(half_t));
  half_t* whh2h = (half_t*)take((size_t)4096 * HDIM * sizeof(half_t));
  half_t* wcomb = (half_t*)take((size_t)4096 * HDIM * sizeof(half_t));
  half_t* wdech = (half_t*)take((size_t)OUTPAD * HDIM * sizeof(half_t));
  half_t* xseqh = (half_t*)take((size_t)TWARM * BATCH * INPAD * sizeof(half_t));
  float*  biasw = (float*) take((size_t)4 * 4096 * sizeof(float));
  float*  bdecw = (float*) take((size_t)OUTPAD * sizeof(float));

  if (ws_size < off) return;  // workspace too small (~62 MB needed)

  hipMemsetAsync(d_ws, 0, zero_bytes, stream);

  k_cvt_pad<<<1024, 256, 0, stream>>>(wih0h, Wih1, INPAD, 4096, INDIM, 4096 * INPAD);
  k_cvt_pad<<<4096, 256, 0, stream>>>(whh0h, Whh1, HDIM, 4096, HDIM, 4096 * HDIM);
  k_cvt_pad<<<4096, 256, 0, stream>>>(wih1h, Wih2, HDIM, 4096, HDIM, 4096 * HDIM);
  k_cvt_pad<<<4096, 256, 0, stream>>>(whh1h, Whh2, HDIM, 4096, HDIM, 4096 * HDIM);
  k_cvt_pad<<<4096, 256, 0, stream>>>(wih2h, Wih3, HDIM, 4096, HDIM, 4096 * HDIM);
  k_cvt_pad<<<4096, 256, 0, stream>>>(whh2h, Whh3, HDIM, 4096, HDIM, 4096 * HDIM);
  k_cvt_pad<<<1024, 256, 0, stream>>>(wdech, Wdec, HDIM, OUTDIM, HDIM, OUTPAD * HDIM);
  k_wcomb<<<1024, 1024, 0, stream>>>(wcomb, Wih1, Wdec);
  k_bias_add<<<16, 256, 0, stream>>>(biasw + 0 * 4096, bih1, bhh1, 4096);
  k_bias_add<<<16, 256, 0, stream>>>(biasw + 1 * 4096, bih2, bhh2, 4096);
  k_bias_add<<<16, 256, 0, stream>>>(biasw + 2 * 4096, bih3, bhh3, 4096);
  k_bgen<<<16, 256, 0, stream>>>(biasw + 3 * 4096, Wih1, bdec, bih1, bhh1);
  k_bias_pad<<<1, 256, 0, stream>>>(bdecw, bdec, OUTDIM, OUTPAD);
  k_xseq<<<2048, 256, 0, stream>>>(xseqh, x_in, TWARM * BATCH * INPAD);

  Params p;
  p.wih0 = wih0h; p.whh0 = whh0h;
  p.wih1 = wih1h; p.whh1 = whh1h;
  p.wih2 = wih2h; p.whh2 = whh2h;
  p.wcomb = wcomb;
  p.bias = biasw; p.wdec = wdech; p.bdec = bdecw;
  p.xseq = xseqh;
  p.h = h_st; p.cT = cT; p.out = (float*)d_out;

  void* args[] = { (void*)&p };
  hipLaunchCooperativeKernel((const void*)lstm_main, dim3(NBLK), dim3(512),
                             args, 0, stream);
}

// Round 12
// 10510.278 us; speedup vs baseline: 1.8609x; 1.2539x over previous
//
#include <hip/hip_runtime.h>
#include <hip/hip_fp16.h>
#include <hip/hip_cooperative_groups.h>
#include <cstdint>
#include <cstddef>

typedef _Float16 half_t;
typedef _Float16 half8  __attribute__((ext_vector_type(8)));
typedef float    float4v __attribute__((ext_vector_type(4)));

#define HDIM   1024
#define INDIM  171
#define INPAD  192     // 171 padded to multiple of 32, zero tail
#define OUTDIM 171
#define OUTPAD 176
#define BATCH  128
#define TWARM  100
#define GGEN   100
#define NSTEP  (TWARM + GGEN)
#define NCELLB 192     // 3 cells x 64 hidx-tiles
#define NDECB  11      // dedicated decoder blocks (on otherwise-idle CUs)
#define NBLK   (NCELLB + NDECB)
#define NGRP   16      // barrier groups

// ---------------------------------------------------------------------------
// R6 post-mortem: dur fit shows cg::grid_group::sync() ~= 62us x 200 = 94% of
// runtime (single-counter contention: 203 serialized device-RMWs + 1624 waves
// polling one line). STANDING EXPERIMENT: custom 2-level hierarchical barrier.
//   - 16 groups (bid&15, ~13 blocks), monotonic counters on separate 256B
//     lines (no reset races)
//   - arrival: acq_rel fetch_add group cnt -> group-last acq_rel fetch_add
//     root -> global-last: release fence + 16 relaxed flag stores
//   - spin: RELAXED agent load + s_sleep backoff, one acquire fence on exit
//     (buffer_inv drops stale per-XCD L2 lines; weights are in VGPRs anyway).
// Everything else unchanged from R6 (weights resident in VGPRs, 1 sync/step,
// decoder fusion via Wcomb, dedicated decoder blocks).
// ---------------------------------------------------------------------------

struct Params {
  const half_t* __restrict__ wih0; const half_t* __restrict__ whh0;
  const half_t* __restrict__ wih1; const half_t* __restrict__ whh1;
  const half_t* __restrict__ wih2; const half_t* __restrict__ whh2;
  const half_t* __restrict__ wcomb;  // [4096][HDIM] = Wih1 @ Wdec
  const float*  __restrict__ bias;   // [4][4096]: c0-warm, c1, c2, c0-gen
  const half_t* __restrict__ wdec;   // [OUTPAD][HDIM]
  const float*  __restrict__ bdec;   // [OUTPAD]
  const half_t* __restrict__ xseq;   // [T][B][INPAD]
  half_t*       __restrict__ h;      // [2][3][B][HDIM] double-buffered
  float*        __restrict__ cT;     // [3][HDIM][B]
  unsigned*     __restrict__ bar;    // barrier: cnt[16],rel[16],root @ stride 64
  float*        __restrict__ out;    // [B][G][OUTDIM]
};

#define MFMA16(a, b, c) __builtin_amdgcn_mfma_f32_16x16x32_f16(a, b, c, 0, 0, 0)

// 2-level grid barrier. gen = step+1 (monotonic, no resets).
__device__ __forceinline__ void gbar(unsigned* bar, int bid, unsigned gen) {
  __syncthreads();                       // all waves' stores drained
  if (threadIdx.x == 0) {
    const int g     = bid & (NGRP - 1);
    const int gsize = (g < (NBLK & (NGRP - 1))) ? (NBLK / NGRP + 1) : (NBLK / NGRP);
    unsigned* cnt  = bar + g * 64;
    unsigned* rel  = bar + (NGRP + g) * 64;
    unsigned* root = bar + 2 * NGRP * 64;
    unsigned old = __hip_atomic_fetch_add(cnt, 1u, __ATOMIC_ACQ_REL,
                                          __HIP_MEMORY_SCOPE_AGENT);
    if (old + 1 == gen * (unsigned)gsize) {            // group-last
      unsigned r = __hip_atomic_fetch_add(root, 1u, __ATOMIC_ACQ_REL,
                                          __HIP_MEMORY_SCOPE_AGENT);
      if (r + 1 == gen * (unsigned)NGRP) {             // global-last: release
        __builtin_amdgcn_fence(__ATOMIC_RELEASE, "agent");
#pragma unroll
        for (int g2 = 0; g2 < NGRP; ++g2)
          __hip_atomic_store(bar + (NGRP + g2) * 64, gen, __ATOMIC_RELAXED,
                             __HIP_MEMORY_SCOPE_AGENT);
      }
    }
    while (__hip_atomic_load(rel, __ATOMIC_RELAXED, __HIP_MEMORY_SCOPE_AGENT) < gen)
      __builtin_amdgcn_s_sleep(2);
    __builtin_amdgcn_fence(__ATOMIC_ACQUIRE, "agent");
  }
  __syncthreads();
}

__device__ __forceinline__ void decoder_tile(const Params& p, int buf, int ob,
                                             int wv, int lr, int lk, int frame) {
  const int b = wv * 16 + lr;
  const half_t* ar = p.wdec + (size_t)(ob + lr) * HDIM + lk * 8;
  const half_t* hr = p.h + (((size_t)buf * 3 + 2) * BATCH + b) * HDIM + lk * 8;
  float4v dacc = (float4v){0.f, 0.f, 0.f, 0.f};
#pragma unroll 4
  for (int ci = 0; ci < (HDIM >> 5); ++ci) {
    const int k0 = ci * 32;
    half8 af = *(const half8*)(ar + k0);
    half8 bf = *(const half8*)(hr + k0);
    dacc = MFMA16(af, bf, dacc);
  }
  const int orow = ob + lk * 4;        // D: col = lane&15 (=b), row = lk*4+r
#pragma unroll
  for (int r = 0; r < 4; ++r)
    if (orow + r < OUTDIM)
      p.out[((size_t)b * GGEN + frame) * OUTDIM + orow + r] = dacc[r] + p.bdec[orow + r];
}

__global__ __launch_bounds__(512, 2) void lstm_main(Params p) {
  const int bid  = blockIdx.x;
  const int tid  = threadIdx.x;
  const int wv   = tid >> 6;
  const int lane = tid & 63;
  const int ggrp = wv & 1;            // gate-pair: 0 -> (i,f), 1 -> (g,o)
  const int kq   = wv >> 1;           // K-quarter 0..3
  const int lr   = lane & 15;         // MFMA: A-row / B-col / D-col
  const int lk   = lane >> 4;         // MFMA: k-group

  __shared__ float Rlds[4][2][16][128];   // 64 KiB: [gate][kq-pair][hidx][b^swz]

  // ---------------- dedicated decoder blocks ----------------
  if (bid >= NCELLB) {
    const int ob = (bid - NCELLB) * 16;
    for (int t = 0; t < NSTEP; ++t) {
      if (t > TWARM) decoder_tile(p, t & 1, ob, wv, lr, lk, t - TWARM - 1);
      gbar(p.bar, bid, t + 1);
    }
    decoder_tile(p, NSTEP & 1, ob, wv, lr, lk, GGEN - 1);
    return;
  }

  // ---------------- cell blocks ----------------
  const int cell = bid >> 6;          // 0..2
  const int m0   = (bid & 63) << 4;   // hidx tile base
  const int jb0  = (2 * ggrp + 0) * HDIM + m0 + lr;   // A row, gate 2g+0
  const int jb1  = (2 * ggrp + 1) * HDIM + m0 + lr;   // A row, gate 2g+1

  // Resident weights (cells 1/2 all steps; cell0: gen-seg0 = wcomb, seg1 = whh0
  // which is valid in BOTH phases):
  const half_t* S0 = (cell == 0) ? p.wcomb : (cell == 1 ? p.wih1 : p.wih2);
  const half_t* S1 = (cell == 0) ? p.whh0  : (cell == 1 ? p.whh1 : p.whh2);

  half8 wA0[16], wA1[16];   // 128 VGPRs resident weights (this wave's quarter)
  {
    const half_t* M  = (kq < 2) ? S0 : S1;
    const int     cb = (kq & 1) * 16;          // local chunk base
#pragma unroll
    for (int ci = 0; ci < 16; ++ci) {
      const size_t ko = (size_t)(cb + ci) * 32 + lk * 8;
      wA0[ci] = *(const half8*)(M + (size_t)jb0 * HDIM + ko);
      wA1[ci] = *(const half8*)(M + (size_t)jb1 * HDIM + ko);
    }
  }

  // Warm-phase cell0 x-part A rows (wih0, ld=INPAD; 1.5 MB, L2-hot stream)
  const half_t* aw00 = p.wih0 + (size_t)jb0 * INPAD + lk * 8;
  const half_t* aw01 = p.wih0 + (size_t)jb1 * INPAD + lk * 8;

  const int csw = (lk & 1) << 4;      // LDS column swizzle (4-way -> free 2-way)

  for (int t = 0; t < NSTEP; ++t) {
    const int cur = t & 1;
    const int nxt = cur ^ 1;
    const bool gen = (t >= TWARM);

    float4v acc0[8], acc1[8];
#pragma unroll
    for (int i = 0; i < 8; ++i) {
      acc0[i] = (float4v){0.f, 0.f, 0.f, 0.f};
      acc1[i] = (float4v){0.f, 0.f, 0.f, 0.f};
    }

    if (cell == 0 && !gen && kq < 2) {
      // ---- streamed x-part: chunks [kq*3, kq*3+3) of INPAD=192 ----
      const half_t* B0 = p.xseq + (size_t)t * BATCH * INPAD;
      const half_t* bx[8];
#pragma unroll
      for (int bt = 0; bt < 8; ++bt) bx[bt] = B0 + (size_t)(bt * 16 + lr) * INPAD + lk * 8;
#pragma unroll
      for (int ci = 0; ci < 3; ++ci) {
        const int ko = (kq * 3 + ci) * 32;
        half8 af0 = *(const half8*)(aw00 + ko);
        half8 af1 = *(const half8*)(aw01 + ko);
#pragma unroll
        for (int bt = 0; bt < 8; ++bt) {
          half8 bf = *(const half8*)(bx[bt] + ko);
          acc0[bt] = MFMA16(af0, bf, acc0[bt]);
          acc1[bt] = MFMA16(af1, bf, acc1[bt]);
        }
      }
    } else {
      // ---- resident-A path ----
      const half_t* bb;
      if (kq < 2) {
        bb = (cell == 0)
            ? p.h + (size_t)(cur * 3 + 2) * BATCH * HDIM            // h2_old (wcomb)
            : p.h + (size_t)(cur * 3 + (cell - 1)) * BATCH * HDIM;  // prev layer OLD h
      } else {
        bb = p.h + (size_t)(cur * 3 + cell) * BATCH * HDIM;         // own OLD h
      }
      const half_t* rb[8];
#pragma unroll
      for (int bt = 0; bt < 8; ++bt)
        rb[bt] = bb + (size_t)(bt * 16 + lr) * HDIM + (kq & 1) * 512 + lk * 8;
#pragma unroll
      for (int ci = 0; ci < 16; ++ci) {
#pragma unroll
        for (int bt = 0; bt < 8; ++bt) {
          half8 bf = *(const half8*)(rb[bt] + ci * 32);
          acc0[bt] = MFMA16(wA0[ci], bf, acc0[bt]);
          acc1[bt] = MFMA16(wA1[ci], bf, acc1[bt]);
        }
      }
    }

    // ---- cross-quarter reduction in LDS (2 phases), D: col=lane&15, row=lk*4+r
    if (kq < 2) {
#pragma unroll
      for (int bt = 0; bt < 8; ++bt) {
        const int col = (bt * 16 + lr) ^ csw;
#pragma unroll
        for (int r = 0; r < 4; ++r) {
          Rlds[2 * ggrp + 0][kq][lk * 4 + r][col] = acc0[bt][r];
          Rlds[2 * ggrp + 1][kq][lk * 4 + r][col] = acc1[bt][r];
        }
      }
    }
    __syncthreads();
    if (kq >= 2) {
#pragma unroll
      for (int bt = 0; bt < 8; ++bt) {
        const int col = (bt * 16 + lr) ^ csw;
#pragma unroll
        for (int r = 0; r < 4; ++r) {
          Rlds[2 * ggrp + 0][kq - 2][lk * 4 + r][col] += acc0[bt][r];
          Rlds[2 * ggrp + 1][kq - 2][lk * 4 + r][col] += acc1[bt][r];
        }
      }
    }
    __syncthreads();

    // ---- elementwise LSTM update: 2048 (hidx,b) cells over 512 threads ----
    const float* biasc = p.bias + ((cell == 0) ? (gen ? 3 : 0) : cell) * 4096;
    float hv[4];
#pragma unroll
    for (int s = 0; s < 4; ++s) {
      const int idx = tid + s * 512;
      const int hl = idx >> 7, b = idx & 127;
      const int bc = b ^ (((hl >> 2) & 1) << 4);
      const float gi = Rlds[0][0][hl][bc] + Rlds[0][1][hl][bc] + biasc[0 * HDIM + m0 + hl];
      const float gf = Rlds[1][0][hl][bc] + Rlds[1][1][hl][bc] + biasc[1 * HDIM + m0 + hl];
      const float gv = Rlds[2][0][hl][bc] + Rlds[2][1][hl][bc] + biasc[2 * HDIM + m0 + hl];
      const float go = Rlds[3][0][hl][bc] + Rlds[3][1][hl][bc] + biasc[3 * HDIM + m0 + hl];
      const float si = 1.f / (1.f + __expf(-gi));
      const float sf = 1.f / (1.f + __expf(-gf));
      const float tg = tanhf(gv);
      const float so = 1.f / (1.f + __expf(-go));
      float* cp = p.cT + ((size_t)cell * HDIM + m0 + hl) * BATCH + b;
      const float cn = sf * (*cp) + si * tg;
      *cp = cn;
      hv[s] = so * tanhf(cn);
    }
    __syncthreads();            // everyone done reading Rlds
    half_t* hbuf = (half_t*)&Rlds[0][0][0][0];   // reuse as [16][128] half
#pragma unroll
    for (int s = 0; s < 4; ++s) {
      const int idx = tid + s * 512;
      hbuf[(idx >> 7) * 128 + (idx & 127)] = (half_t)hv[s];
    }
    __syncthreads();
    // transpose to b-major fp16 rows for next step's MFMA B operand
    if (tid < 256) {
      const int b = tid & 127, seg = tid >> 7;
      half_t vals[8];
#pragma unroll
      for (int q = 0; q < 8; ++q) vals[q] = hbuf[(seg * 8 + q) * 128 + b];
      half_t* hd = p.h + ((size_t)(nxt * 3 + cell) * BATCH + b) * HDIM + m0 + seg * 8;
      *(half8*)hd = *(const half8*)vals;
    }

    gbar(p.bar, bid, t + 1);   // ONE barrier per step — publishes h(t+1)
  }
}

// --------------------------- init / conversion -----------------------------

__global__ void k_cvt_pad(half_t* __restrict__ dst, const float* __restrict__ src,
                          int dcols, int srows, int scols, int n) {
  for (int i = blockIdx.x * blockDim.x + threadIdx.x; i < n; i += gridDim.x * blockDim.x) {
    const int r = i / dcols, c = i - r * dcols;
    const float v = (r < srows && c < scols) ? src[(size_t)r * scols + c] : 0.f;
    dst[i] = (half_t)v;
  }
}

__global__ void k_bias_add(float* __restrict__ dst, const float* __restrict__ a,
                           const float* __restrict__ b, int n) {
  const int i = blockIdx.x * blockDim.x + threadIdx.x;
  if (i < n) dst[i] = a[i] + b[i];
}

__global__ void k_bias_pad(float* __restrict__ dst, const float* __restrict__ src,
                           int nsrc, int n) {
  const int i = blockIdx.x * blockDim.x + threadIdx.x;
  if (i < n) dst[i] = (i < nsrc) ? src[i] : 0.f;
}

// Wcomb = Wih1 @ Wdec : (4096,171)x(171,1024) -> fp16 [4096][1024]
__global__ void k_wcomb(half_t* __restrict__ dst, const float* __restrict__ wih,
                        const float* __restrict__ wdec) {
  const int j0 = blockIdx.x * 4;
  const int k  = threadIdx.x;
  float acc0 = 0.f, acc1 = 0.f, acc2 = 0.f, acc3 = 0.f;
  for (int c = 0; c < OUTDIM; ++c) {
    const float d = wdec[(size_t)c * HDIM + k];
    acc0 += wih[(size_t)(j0 + 0) * INDIM + c] * d;
    acc1 += wih[(size_t)(j0 + 1) * INDIM + c] * d;
    acc2 += wih[(size_t)(j0 + 2) * INDIM + c] * d;
    acc3 += wih[(size_t)(j0 + 3) * INDIM + c] * d;
  }
  dst[(size_t)(j0 + 0) * HDIM + k] = (half_t)acc0;
  dst[(size_t)(j0 + 1) * HDIM + k] = (half_t)acc1;
  dst[(size_t)(j0 + 2) * HDIM + k] = (half_t)acc2;
  dst[(size_t)(j0 + 3) * HDIM + k] = (half_t)acc3;
}

// gen-phase cell0 bias: bih + bhh + Wih1 @ bdec
__global__ void k_bgen(float* __restrict__ dst, const float* __restrict__ wih,
                       const float* __restrict__ bdec, const float* __restrict__ bih,
                       const float* __restrict__ bhh) {
  const int j = blockIdx.x * 256 + threadIdx.x;
  float a = 0.f;
  for (int c = 0; c < OUTDIM; ++c) a += wih[(size_t)j * INDIM + c] * bdec[c];
  dst[j] = a + bih[j] + bhh[j];
}

// initial_seq [B][T][171] fp32 -> [T][B][INPAD] fp16 (zero-padded cols)
__global__ void k_xseq(half_t* __restrict__ dst, const float* __restrict__ src, int n) {
  for (int i = blockIdx.x * blockDim.x + threadIdx.x; i < n; i += gridDim.x * blockDim.x) {
    const int t   = i / (BATCH * INPAD);
    const int rem = i - t * BATCH * INPAD;
    const int b   = rem / INPAD;
    const int c   = rem - b * INPAD;
    const float v = (c < INDIM) ? src[((size_t)b * TWARM + t) * INDIM + c] : 0.f;
    dst[i] = (half_t)v;
  }
}

// ---------------------------------------------------------------------------

extern "C" void kernel_launch(void* const* d_in, const int* in_sizes, int n_in,
                              void* d_out, int out_size, void* d_ws, size_t ws_size,
                              hipStream_t stream) {
  const float* x_in = (const float*)d_in[0];
  const float* Wih1 = (const float*)d_in[1];
  const float* Whh1 = (const float*)d_in[2];
  const float* bih1 = (const float*)d_in[3];
  const float* bhh1 = (const float*)d_in[4];
  const float* Wih2 = (const float*)d_in[5];
  const float* Whh2 = (const float*)d_in[6];
  const float* bih2 = (const float*)d_in[7];
  const float* bhh2 = (const float*)d_in[8];
  const float* Wih3 = (const float*)d_in[9];
  const float* Whh3 = (const float*)d_in[10];
  const float* bih3 = (const float*)d_in[11];
  const float* bhh3 = (const float*)d_in[12];
  const float* Wdec = (const float*)d_in[13];
  const float* bdec = (const float*)d_in[14];

  char* ws = (char*)d_ws;
  size_t off = 0;
  auto take = [&](size_t bytes) -> char* {
    char* p = ws + off;
    off += (bytes + 255) & ~(size_t)255;
    return p;
  };

  // zero-init region first (d_ws is poisoned 0xAA before every launch)
  half_t*   h_st = (half_t*)  take((size_t)2 * 3 * BATCH * HDIM * sizeof(half_t));
  float*    cT   = (float*)   take((size_t)3 * HDIM * BATCH * sizeof(float));
  unsigned* bar  = (unsigned*)take((size_t)(2 * NGRP + 1) * 64 * sizeof(unsigned));
  const size_t zero_bytes = off;

  half_t* wih0h = (half_t*)take((size_t)4096 * INPAD * sizeof(half_t));
  half_t* whh0h = (half_t*)take((size_t)4096 * HDIM * sizeof(half_t));
  half_t* wih1h = (half_t*)take((size_t)4096 * HDIM * sizeof(half_t));
  half_t* whh1h = (half_t*)take((size_t)4096 * HDIM * sizeof(half_t));
  half_t* wih2h = (half_t*)take((size_t)4096 * HDIM * sizeof(half_t));
  half_t* whh2h = (half_t*)take((size_t)4096 * HDIM * sizeof(half_t));
  half_t* wcomb = (half_t*)take((size_t)4096 * HDIM * sizeof(half_t));
  half_t* wdech = (half_t*)take((size_t)OUTPAD * HDIM * sizeof(half_t));
  half_t* xseqh = (half_t*)take((size_t)TWARM * BATCH * INPAD * sizeof(half_t));
  float*  biasw = (float*) take((size_t)4 * 4096 * sizeof(float));
  float*  bdecw = (float*) take((size_t)OUTPAD * sizeof(float));

  if (ws_size < off) return;  // workspace too small (~62 MB needed)

  hipMemsetAsync(d_ws, 0, zero_bytes, stream);

  k_cvt_pad<<<1024, 256, 0, stream>>>(wih0h, Wih1, INPAD, 4096, INDIM, 4096 * INPAD);
  k_cvt_pad<<<4096, 256, 0, stream>>>(whh0h, Whh1, HDIM, 4096, HDIM, 4096 * HDIM);
  k_cvt_pad<<<4096, 256, 0, stream>>>(wih1h, Wih2, HDIM, 4096, HDIM, 4096 * HDIM);
  k_cvt_pad<<<4096, 256, 0, stream>>>(whh1h, Whh2, HDIM, 4096, HDIM, 4096 * HDIM);
  k_cvt_pad<<<4096, 256, 0, stream>>>(wih2h, Wih3, HDIM, 4096, HDIM, 4096 * HDIM);
  k_cvt_pad<<<4096, 256, 0, stream>>>(whh2h, Whh3, HDIM, 4096, HDIM, 4096 * HDIM);
  k_cvt_pad<<<1024, 256, 0, stream>>>(wdech, Wdec, HDIM, OUTDIM, HDIM, OUTPAD * HDIM);
  k_wcomb<<<1024, 1024, 0, stream>>>(wcomb, Wih1, Wdec);
  k_bias_add<<<16, 256, 0, stream>>>(biasw + 0 * 4096, bih1, bhh1, 4096);
  k_bias_add<<<16, 256, 0, stream>>>(biasw + 1 * 4096, bih2, bhh2, 4096);
  k_bias_add<<<16, 256, 0, stream>>>(biasw + 2 * 4096, bih3, bhh3, 4096);
  k_bgen<<<16, 256, 0, stream>>>(biasw + 3 * 4096, Wih1, bdec, bih1, bhh1);
  k_bias_pad<<<1, 256, 0, stream>>>(bdecw, bdec, OUTDIM, OUTPAD);
  k_xseq<<<2048, 256, 0, stream>>>(xseqh, x_in, TWARM * BATCH * INPAD);

  Params p;
  p.wih0 = wih0h; p.whh0 = whh0h;
  p.wih1 = wih1h; p.whh1 = whh1h;
  p.wih2 = wih2h; p.whh2 = whh2h;
  p.wcomb = wcomb;
  p.bias = biasw; p.wdec = wdech; p.bdec = bdecw;
  p.xseq = xseqh;
  p.h = h_st; p.cT = cT; p.bar = bar; p.out = (float*)d_out;

  void* args[] = { (void*)&p };
  hipLaunchCooperativeKernel((const void*)lstm_main, dim3(NBLK), dim3(512),
                             args, 0, stream);
}